// Round 1
// baseline (3200.621 us; speedup 1.0000x reference)
//
#include <hip/hip_runtime.h>
#include <cmath>

// WaterNet: NH=128, NG=32, NR=15, NT=730, NS=800
#define NHID 128
#define NSITE 800
#define NTIME 730
#define NRTAP 15
constexpr int NSH = NSITE * NHID;  // 102400

__device__ __forceinline__ float tanh_fast(float x) {
    // exact identity tanh(x) = 1 - 2/(exp(2x)+1); __expf saturates cleanly
    float e = __expf(2.0f * x);
    return 1.0f - 2.0f / (e + 1.0f);
}
__device__ __forceinline__ float sigmoid_fast(float x) {
    return 1.0f / (1.0f + __expf(-x));
}

// ---------------------------------------------------------------------------
// A1: per-site layer-1 for all three heads.
//   h1w = tanh(xc@fcW1_w + b), h1r = tanh(xc@fcR1_w + b),
//   basec = xc@fcT1_w[6:38] + fcT1_b   (pre-activation; x-part added later)
// grid: 800 blocks x 256 threads
// ---------------------------------------------------------------------------
__global__ void k_site_l1(const float* __restrict__ xc,
                          const float* __restrict__ w1W, const float* __restrict__ b1W,
                          const float* __restrict__ w1R, const float* __restrict__ b1R,
                          const float* __restrict__ w1T, const float* __restrict__ b1T,
                          float* __restrict__ h1w, float* __restrict__ h1r,
                          float* __restrict__ basec)
{
    __shared__ float xr[32];
    int s = blockIdx.x, j = threadIdx.x;
    if (j < 32) xr[j] = xc[s * 32 + j];
    __syncthreads();
    float aW = b1W[j], aR = b1R[j], aT = b1T[j];
#pragma unroll 8
    for (int k = 0; k < 32; ++k) {
        float xv = xr[k];
        aW = fmaf(xv, w1W[k * 256 + j], aW);
        aR = fmaf(xv, w1R[k * 256 + j], aR);
        aT = fmaf(xv, w1T[(6 + k) * 256 + j], aT);
    }
    h1w[s * 256 + j]   = tanh_fast(aW);
    h1r[s * 256 + j]   = tanh_fast(aR);
    basec[s * 256 + j] = aT;
}

// ---------------------------------------------------------------------------
// A2: static parameter head layer-2 + activations.
// grid: (100 site-groups of 8, 7 param groups) x 128 threads
// params layout: [7][NSITE*NHID], g in {kp,ks,kg,gp,gL,qb,ga_raw}
// ---------------------------------------------------------------------------
__global__ void k_whead(const float* __restrict__ h1w,
                        const float* __restrict__ w2, const float* __restrict__ b2,
                        float* __restrict__ params)
{
    __shared__ float h[8 * 256];
    int sBase = blockIdx.x * 8, g = blockIdx.y, tid = threadIdx.x;
    for (int p = tid; p < 2048; p += 128) h[p] = h1w[sBase * 256 + p];
    __syncthreads();
    float bias = b2[g * 128 + tid];
    float acc[8];
#pragma unroll
    for (int i = 0; i < 8; ++i) acc[i] = bias;
    for (int k = 0; k < 256; ++k) {
        float wv = w2[k * 896 + g * 128 + tid];
#pragma unroll
        for (int i = 0; i < 8; ++i) acc[i] = fmaf(h[i * 256 + k], wv, acc[i]);
    }
#pragma unroll
    for (int i = 0; i < 8; ++i) {
        float v = acc[i], o;
        if (g == 0 || g == 1 || g == 3)  o = sigmoid_fast(v);
        else if (g == 2)                 o = sigmoid_fast(v) * 0.1f;
        else if (g == 4)                 o = __expf(v) * 2.0f;
        else if (g == 5)                 o = fmaxf(v, 0.0f);
        else                             o = v;  // ga raw (softmax later)
        params[g * NSH + (sBase + i) * 128 + tid] = o;
    }
}

// ---------------------------------------------------------------------------
// A3: softmax of ga over the 128 hidden buckets, in place.
// grid: 800 blocks x 128 threads
// ---------------------------------------------------------------------------
__global__ void k_softmax_ga(float* __restrict__ ga)
{
    int s = blockIdx.x, h = threadIdx.x;
    float v = ga[s * 128 + h];
    float m = v;
#pragma unroll
    for (int off = 32; off; off >>= 1) m = fmaxf(m, __shfl_xor(m, off));
    __shared__ float ra[2], rb[2];
    if ((h & 63) == 0) ra[h >> 6] = m;
    __syncthreads();
    m = fmaxf(ra[0], ra[1]);
    float e = __expf(v - m);
    float t = e;
#pragma unroll
    for (int off = 32; off; off >>= 1) t += __shfl_xor(t, off);
    if ((h & 63) == 0) rb[h >> 6] = t;
    __syncthreads();
    ga[s * 128 + h] = e / (rb[0] + rb[1]);
}

// ---------------------------------------------------------------------------
// A4: routing-kernel head layer-2, r = relu(.), stored as [NRTAP][NSITE*NHID]
// grid: (100, 15) x 128 threads; group g covers cols g*128 .. g*128+127 of 1920
// ---------------------------------------------------------------------------
__global__ void k_rhead(const float* __restrict__ h1r,
                        const float* __restrict__ w2, const float* __restrict__ b2,
                        float* __restrict__ rbuf)
{
    __shared__ float h[8 * 256];
    int sBase = blockIdx.x * 8, g = blockIdx.y, tid = threadIdx.x;
    for (int p = tid; p < 2048; p += 128) h[p] = h1r[sBase * 256 + p];
    __syncthreads();
    int c = g * 128 + tid;
    float bias = b2[c];
    float acc[8];
#pragma unroll
    for (int i = 0; i < 8; ++i) acc[i] = bias;
    for (int k = 0; k < 256; ++k) {
        float wv = w2[k * 1920 + c];
#pragma unroll
        for (int i = 0; i < 8; ++i) acc[i] = fmaf(h[i * 256 + k], wv, acc[i]);
    }
    int hh = c / 15, ii = c - hh * 15;
#pragma unroll
    for (int i = 0; i < 8; ++i)
        rbuf[ii * NSH + (sBase + i) * 128 + hh] = fmaxf(acc[i], 0.0f);
}

// ---------------------------------------------------------------------------
// B: time-varying head for one chunk of Tc timesteps.
// GEMM rows = Tc*800 (row = tloc*800 + s), K=256, N=384 (3 channel groups).
// Writes PL = P(1-vf)*vi, EV = E*ve, VM = exp(v), PS = P*vf.
// grid: (ceil(rows/32), 3) x 256 threads
// ---------------------------------------------------------------------------
#define BM 32
__global__ __launch_bounds__(256) void k_timehead(
    const float* __restrict__ x, const float* __restrict__ w1T,
    const float* __restrict__ basec,
    const float* __restrict__ w2, const float* __restrict__ b2,
    float* __restrict__ PL, float* __restrict__ EV, float* __restrict__ VM,
    float* __restrict__ PS, int t0, int rowsC)
{
    __shared__ float h1[BM][257];
    __shared__ __align__(16) float w2t[32][128];
    __shared__ float xt[BM][6];
    __shared__ float pls[BM], evs[BM];

    int m0 = blockIdx.x * BM;
    int ch = blockIdx.y;           // 0: vi->PL, 1: ve->EV, 2: vm->VM
    int n0 = ch * 128;
    int tid = threadIdx.x;

    // stage x tile (64? no: 32 rows x 6 forcings)
    if (tid < BM * 6) {
        int r = tid / 6, cc = tid - r * 6;
        int row = m0 + r;
        xt[r][cc] = (row < rowsC) ? x[(size_t)(t0 * 800 + row) * 6 + cc] : 0.0f;
    }
    __syncthreads();

    // per-row snow fraction scalars
    if (tid < BM) {
        int r = tid, row = m0 + r;
        float P = xt[r][0], E = xt[r][1], T1 = xt[r][2], T2 = xt[r][3];
        float den = T2 - T1;
        float cf = (T1 + T2) / ((den == 0.0f) ? 1.0f : den);
        cf = fminf(fmaxf(cf, -0.999999f), 0.999999f);
        float vf = acosf(cf) * (1.0f / 3.1415f);
        vf = (T1 >= 0.0f) ? 0.0f : vf;
        vf = (T2 <= 0.0f) ? 1.0f : vf;
        pls[r] = P * (1.0f - vf);
        evs[r] = E;
        if (ch == 0 && row < rowsC) PS[row] = P * vf;
    }

    // layer 1: thread tid owns column j = tid for all BM rows
    {
        int j = tid;
        float wx0 = w1T[0 * 256 + j], wx1 = w1T[1 * 256 + j], wx2 = w1T[2 * 256 + j];
        float wx3 = w1T[3 * 256 + j], wx4 = w1T[4 * 256 + j], wx5 = w1T[5 * 256 + j];
#pragma unroll 4
        for (int r = 0; r < BM; ++r) {
            int row = m0 + r;
            float v = 0.0f;
            if (row < rowsC) {
                int s = row % 800;
                float a = basec[s * 256 + j];
                a = fmaf(xt[r][0], wx0, a);
                a = fmaf(xt[r][1], wx1, a);
                a = fmaf(xt[r][2], wx2, a);
                a = fmaf(xt[r][3], wx3, a);
                a = fmaf(xt[r][4], wx4, a);
                a = fmaf(xt[r][5], wx5, a);
                v = tanh_fast(a);
            }
            h1[r][j] = v;
        }
    }

    // layer 2 GEMM: thread tile 2 rows x 8 cols
    int ty = tid >> 4, tx = tid & 15;
    float acc[2][8];
#pragma unroll
    for (int ci = 0; ci < 8; ++ci) {
        float bb = b2[n0 + tx * 8 + ci];
        acc[0][ci] = bb;
        acc[1][ci] = bb;
    }
    for (int k0 = 0; k0 < 256; k0 += 32) {
        __syncthreads();
        for (int l = tid; l < 1024; l += 256) {
            int kk = l >> 5, c4 = l & 31;
            *(float4*)&w2t[kk][c4 * 4] =
                *(const float4*)&w2[(size_t)(k0 + kk) * 384 + n0 + c4 * 4];
        }
        __syncthreads();
#pragma unroll
        for (int kk = 0; kk < 32; ++kk) {
            float a0 = h1[ty * 2 + 0][k0 + kk];
            float a1 = h1[ty * 2 + 1][k0 + kk];
            float4 bq0 = *(float4*)&w2t[kk][tx * 8];
            float4 bq1 = *(float4*)&w2t[kk][tx * 8 + 4];
            acc[0][0] = fmaf(a0, bq0.x, acc[0][0]);
            acc[0][1] = fmaf(a0, bq0.y, acc[0][1]);
            acc[0][2] = fmaf(a0, bq0.z, acc[0][2]);
            acc[0][3] = fmaf(a0, bq0.w, acc[0][3]);
            acc[0][4] = fmaf(a0, bq1.x, acc[0][4]);
            acc[0][5] = fmaf(a0, bq1.y, acc[0][5]);
            acc[0][6] = fmaf(a0, bq1.z, acc[0][6]);
            acc[0][7] = fmaf(a0, bq1.w, acc[0][7]);
            acc[1][0] = fmaf(a1, bq0.x, acc[1][0]);
            acc[1][1] = fmaf(a1, bq0.y, acc[1][1]);
            acc[1][2] = fmaf(a1, bq0.z, acc[1][2]);
            acc[1][3] = fmaf(a1, bq0.w, acc[1][3]);
            acc[1][4] = fmaf(a1, bq1.x, acc[1][4]);
            acc[1][5] = fmaf(a1, bq1.y, acc[1][5]);
            acc[1][6] = fmaf(a1, bq1.z, acc[1][6]);
            acc[1][7] = fmaf(a1, bq1.w, acc[1][7]);
        }
    }

    // epilogue: channel-specific activation + forcing folding
    float* dst = (ch == 0) ? PL : ((ch == 1) ? EV : VM);
#pragma unroll
    for (int ri = 0; ri < 2; ++ri) {
        int r = ty * 2 + ri, row = m0 + r;
        if (row >= rowsC) continue;
        float vals[8];
#pragma unroll
        for (int ci = 0; ci < 8; ++ci) {
            float v = acc[ri][ci];
            if (ch == 0) {
                float vi = fminf(fmaxf(v * (1.0f / 3.0f) + 0.5f, 0.0f), 1.0f);
                vals[ci] = pls[r] * vi;
            } else if (ch == 1) {
                vals[ci] = evs[r] * fmaxf(v, 0.0f) * 2.0f;
            } else {
                vals[ci] = __expf(v);
            }
        }
        float4 o0 = make_float4(vals[0], vals[1], vals[2], vals[3]);
        float4 o1 = make_float4(vals[4], vals[5], vals[6], vals[7]);
        *(float4*)&dst[(size_t)row * 128 + tx * 8]     = o0;
        *(float4*)&dst[(size_t)row * 128 + tx * 8 + 4] = o1;
    }
}

// ---------------------------------------------------------------------------
// C: sequential reservoir scan for one chunk + fused FIR routing + ga-reduce.
// grid: 800 blocks (site) x 128 threads (bucket). State persists in ws.
// ---------------------------------------------------------------------------
__global__ __launch_bounds__(128) void k_scan(
    const float* __restrict__ PL, const float* __restrict__ EV,
    const float* __restrict__ VM, const float* __restrict__ PS,
    const float* __restrict__ params, const float* __restrict__ rbuf,
    float* __restrict__ state, float* __restrict__ fut,
    float* __restrict__ out, int t0, int Tc, int isFirst)
{
    int s = blockIdx.x, h = threadIdx.x;
    int idx = s * 128 + h;

    float kp = params[0 * NSH + idx];
    float ks = params[1 * NSH + idx];
    float kg = params[2 * NSH + idx];
    float gp = params[3 * NSH + idx];
    float gL = params[4 * NSH + idx];
    float qb = params[5 * NSH + idx];
    float ga = params[6 * NSH + idx];
    float kq = ks * (1.0f - gp);

    float r[NRTAP];
#pragma unroll
    for (int i = 0; i < NRTAP; ++i) r[i] = rbuf[i * NSH + idx];

    float Sf, Ss, Sg, f[NRTAP];
    if (isFirst) {
        Sf = Ss = Sg = 0.0f;
#pragma unroll
        for (int i = 0; i < NRTAP; ++i) f[i] = 0.0f;
    } else {
        Sf = state[idx];
        Ss = state[NSH + idx];
        Sg = state[2 * NSH + idx];
#pragma unroll
        for (int i = 0; i < NRTAP; ++i) f[i] = fut[i * NSH + idx];
    }

    __shared__ float red[2][2];

    float pl0 = PL[idx], ev0 = EV[idx], vm0 = VM[idx], ps0 = PS[s];
    for (int t = 0; t < Tc; ++t) {
        // prefetch next step (independent loads issued before the compute)
        float pl1 = 0.0f, ev1 = 0.0f, vm1 = 0.0f, ps1 = 0.0f;
        if (t + 1 < Tc) {
            size_t o = (size_t)(t + 1) * NSH + idx;
            pl1 = PL[o]; ev1 = EV[o]; vm1 = VM[o];
            ps1 = PS[(t + 1) * 800 + s];
        }

        float x1 = Sf + ps0;
        float qf = fminf(x1, vm0);
        Sf = fmaxf(x1 - vm0, 0.0f);
        float H  = fmaxf(Ss + pl0 + qf - ev0, 0.0f);
        float qp = fmaxf(kp * (H - gL), 0.0f);
        float mh = fminf(H, gL);
        float qs = ks * mh;
        Ss = H - qp - qs;
        float qg = fmaf(kg, fmaf(qs, gp, Sg), qb);
        Sg = Sg - qg;
        float qt = qp + kq * mh + qg;

#pragma unroll
        for (int i = 0; i < NRTAP; ++i) f[i] = fmaf(r[i], qt, f[i]);
        float c = ga * f[0];
#pragma unroll
        for (int i = 0; i < NRTAP - 1; ++i) f[i] = f[i + 1];
        f[NRTAP - 1] = 0.0f;

#pragma unroll
        for (int off = 32; off; off >>= 1) c += __shfl_xor(c, off);
        if ((h & 63) == 0) red[t & 1][h >> 6] = c;
        __syncthreads();
        if (h == 0) out[(size_t)(t0 + t) * 800 + s] = red[t & 1][0] + red[t & 1][1];

        pl0 = pl1; ev0 = ev1; vm0 = vm1; ps0 = ps1;
    }

    state[idx]           = Sf;
    state[NSH + idx]     = Ss;
    state[2 * NSH + idx] = Sg;
#pragma unroll
    for (int i = 0; i < NRTAP; ++i) fut[i * NSH + idx] = f[i];
}

// ---------------------------------------------------------------------------
extern "C" void kernel_launch(void* const* d_in, const int* in_sizes, int n_in,
                              void* d_out, int out_size, void* d_ws, size_t ws_size,
                              hipStream_t stream)
{
    const float* x      = (const float*)d_in[0];
    const float* xc     = (const float*)d_in[1];
    const float* fcW1_w = (const float*)d_in[2];
    const float* fcW1_b = (const float*)d_in[3];
    const float* fcW2_w = (const float*)d_in[4];
    const float* fcW2_b = (const float*)d_in[5];
    const float* fcT1_w = (const float*)d_in[6];
    const float* fcT1_b = (const float*)d_in[7];
    const float* fcT2_w = (const float*)d_in[8];
    const float* fcT2_b = (const float*)d_in[9];
    const float* fcR1_w = (const float*)d_in[10];
    const float* fcR1_b = (const float*)d_in[11];
    const float* fcR2_w = (const float*)d_in[12];
    const float* fcR2_b = (const float*)d_in[13];
    float* out = (float*)d_out;

    float* ws = (float*)d_ws;
    size_t off = 0;
    float* params = ws + off; off += (size_t)7 * NSH;      // 716800
    float* rbuf   = ws + off; off += (size_t)NRTAP * NSH;  // 1536000
    float* basec  = ws + off; off += 800 * 256;
    float* h1w    = ws + off; off += 800 * 256;
    float* h1r    = ws + off; off += 800 * 256;
    float* state  = ws + off; off += (size_t)3 * NSH;
    float* fut    = ws + off; off += (size_t)NRTAP * NSH;
    size_t fixedF = off;                                    // 4,710,400 floats

    long availF = (long)(ws_size / 4) - (long)fixedF;
    long perT   = 800 + (long)3 * NSH;                      // 308,000 floats/step
    int Tc = (int)(availF / perT);
    if (Tc > NTIME) Tc = NTIME;
    if (Tc < 1) Tc = 1;

    float* PS = ws + off; off += (size_t)Tc * 800;
    float* PL = ws + off; off += (size_t)Tc * NSH;
    float* EV = ws + off; off += (size_t)Tc * NSH;
    float* VM = ws + off; off += (size_t)Tc * NSH;

    k_site_l1<<<800, 256, 0, stream>>>(xc, fcW1_w, fcW1_b, fcR1_w, fcR1_b,
                                       fcT1_w, fcT1_b, h1w, h1r, basec);
    k_whead<<<dim3(100, 7), 128, 0, stream>>>(h1w, fcW2_w, fcW2_b, params);
    k_softmax_ga<<<800, 128, 0, stream>>>(params + (size_t)6 * NSH);
    k_rhead<<<dim3(100, 15), 128, 0, stream>>>(h1r, fcR2_w, fcR2_b, rbuf);

    int nchunk = (NTIME + Tc - 1) / Tc;
    for (int c = 0; c < nchunk; ++c) {
        int t0 = c * Tc;
        int Tcc = NTIME - t0; if (Tcc > Tc) Tcc = Tc;
        int rowsC = Tcc * 800;
        dim3 gB((rowsC + BM - 1) / BM, 3);
        k_timehead<<<gB, 256, 0, stream>>>(x, fcT1_w, basec, fcT2_w, fcT2_b,
                                           PL, EV, VM, PS, t0, rowsC);
        k_scan<<<800, 128, 0, stream>>>(PL, EV, VM, PS, params, rbuf,
                                        state, fut, out, t0, Tcc, c == 0 ? 1 : 0);
    }
}

// Round 2
// 994.324 us; speedup vs baseline: 3.2189x; 3.2189x over previous
//
#include <hip/hip_runtime.h>
#include <cmath>

// WaterNet: NH=128, NG=32, NR=15, NT=730, NS=800
#define NHID 128
#define NSITE 800
#define NTIME 730
#define NRTAP 15
constexpr int NSH = NSITE * NHID;  // 102400

typedef _Float16 f16x8 __attribute__((ext_vector_type(8)));
typedef float f32x4 __attribute__((ext_vector_type(4)));

__device__ __forceinline__ float tanh_fast(float x) {
    float e = __expf(2.0f * x);
    return 1.0f - 2.0f / (e + 1.0f);
}
__device__ __forceinline__ float sigmoid_fast(float x) {
    return 1.0f / (1.0f + __expf(-x));
}

// ---------------------------------------------------------------------------
// P0: convert fcT2_w (fp32 [256][384]) to fp16 in MFMA-staging layout:
//   w2s[K0][kg][col][e] , k = K0*32 + kg*8 + e   (f16x8-chunk per (kg,col))
// ---------------------------------------------------------------------------
__global__ void k_prep_w2h(const float* __restrict__ w2, _Float16* __restrict__ w2s)
{
    int idx = blockIdx.x * 256 + threadIdx.x;   // 256*384 = 98304
    if (idx >= 98304) return;
    int k = idx / 384, col = idx - k * 384;
    int K0 = k >> 5, kg = (k >> 3) & 3, e = k & 7;
    w2s[(size_t)K0 * 12288 + kg * 3072 + col * 8 + e] = (_Float16)w2[(size_t)k * 384 + col];
}

// ---------------------------------------------------------------------------
// A1: per-site layer-1 for all three heads.
// ---------------------------------------------------------------------------
__global__ void k_site_l1(const float* __restrict__ xc,
                          const float* __restrict__ w1W, const float* __restrict__ b1W,
                          const float* __restrict__ w1R, const float* __restrict__ b1R,
                          const float* __restrict__ w1T, const float* __restrict__ b1T,
                          float* __restrict__ h1w, float* __restrict__ h1r,
                          float* __restrict__ basec)
{
    __shared__ float xr[32];
    int s = blockIdx.x, j = threadIdx.x;
    if (j < 32) xr[j] = xc[s * 32 + j];
    __syncthreads();
    float aW = b1W[j], aR = b1R[j], aT = b1T[j];
#pragma unroll 8
    for (int k = 0; k < 32; ++k) {
        float xv = xr[k];
        aW = fmaf(xv, w1W[k * 256 + j], aW);
        aR = fmaf(xv, w1R[k * 256 + j], aR);
        aT = fmaf(xv, w1T[(6 + k) * 256 + j], aT);
    }
    h1w[s * 256 + j]   = tanh_fast(aW);
    h1r[s * 256 + j]   = tanh_fast(aR);
    basec[s * 256 + j] = aT;
}

// ---------------------------------------------------------------------------
// A2: static parameter head layer-2 + activations.
// ---------------------------------------------------------------------------
__global__ void k_whead(const float* __restrict__ h1w,
                        const float* __restrict__ w2, const float* __restrict__ b2,
                        float* __restrict__ params)
{
    __shared__ float h[8 * 256];
    int sBase = blockIdx.x * 8, g = blockIdx.y, tid = threadIdx.x;
    for (int p = tid; p < 2048; p += 128) h[p] = h1w[sBase * 256 + p];
    __syncthreads();
    float bias = b2[g * 128 + tid];
    float acc[8];
#pragma unroll
    for (int i = 0; i < 8; ++i) acc[i] = bias;
    for (int k = 0; k < 256; ++k) {
        float wv = w2[k * 896 + g * 128 + tid];
#pragma unroll
        for (int i = 0; i < 8; ++i) acc[i] = fmaf(h[i * 256 + k], wv, acc[i]);
    }
#pragma unroll
    for (int i = 0; i < 8; ++i) {
        float v = acc[i], o;
        if (g == 0 || g == 1 || g == 3)  o = sigmoid_fast(v);
        else if (g == 2)                 o = sigmoid_fast(v) * 0.1f;
        else if (g == 4)                 o = __expf(v) * 2.0f;
        else if (g == 5)                 o = fmaxf(v, 0.0f);
        else                             o = v;  // ga raw (softmax later)
        params[g * NSH + (sBase + i) * 128 + tid] = o;
    }
}

// ---------------------------------------------------------------------------
// A3: softmax of ga over the 128 hidden buckets, in place.
// ---------------------------------------------------------------------------
__global__ void k_softmax_ga(float* __restrict__ ga)
{
    int s = blockIdx.x, h = threadIdx.x;
    float v = ga[s * 128 + h];
    float m = v;
#pragma unroll
    for (int off = 32; off; off >>= 1) m = fmaxf(m, __shfl_xor(m, off));
    __shared__ float ra[2], rb[2];
    if ((h & 63) == 0) ra[h >> 6] = m;
    __syncthreads();
    m = fmaxf(ra[0], ra[1]);
    float e = __expf(v - m);
    float t = e;
#pragma unroll
    for (int off = 32; off; off >>= 1) t += __shfl_xor(t, off);
    if ((h & 63) == 0) rb[h >> 6] = t;
    __syncthreads();
    ga[s * 128 + h] = e / (rb[0] + rb[1]);
}

// ---------------------------------------------------------------------------
// A4: routing head layer-2, r = relu(.), stored as [NRTAP][NSITE*NHID]
// ---------------------------------------------------------------------------
__global__ void k_rhead(const float* __restrict__ h1r,
                        const float* __restrict__ w2, const float* __restrict__ b2,
                        float* __restrict__ rbuf)
{
    __shared__ float h[8 * 256];
    int sBase = blockIdx.x * 8, g = blockIdx.y, tid = threadIdx.x;
    for (int p = tid; p < 2048; p += 128) h[p] = h1r[sBase * 256 + p];
    __syncthreads();
    int c = g * 128 + tid;
    float bias = b2[c];
    float acc[8];
#pragma unroll
    for (int i = 0; i < 8; ++i) acc[i] = bias;
    for (int k = 0; k < 256; ++k) {
        float wv = w2[k * 1920 + c];
#pragma unroll
        for (int i = 0; i < 8; ++i) acc[i] = fmaf(h[i * 256 + k], wv, acc[i]);
    }
    int hh = c / 15, ii = c - hh * 15;
#pragma unroll
    for (int i = 0; i < 8; ++i)
        rbuf[ii * NSH + (sBase + i) * 128 + hh] = fmaxf(acc[i], 0.0f);
}

// ---------------------------------------------------------------------------
// B: time-varying head via fp16 MFMA.
// Block: 64 rows x 384 cols. 4 waves, wave w owns cols [w*96, w*96+96).
// A (h1, computed in-kernel) in LDS layout Ah[ks=8][kg=4][row=64] f16x8
//   -> frag read: lanes 0..15 hit 256 contiguous bytes (conflict-free).
// B (w2 fp16, pre-laid-out) staged per k-step: Bh[kg=4][col=384] f16x8.
// ---------------------------------------------------------------------------
__global__ __launch_bounds__(256, 2) void k_timehead_mfma(
    const float* __restrict__ x, const float* __restrict__ w1T,
    const float* __restrict__ basec, const f16x8* __restrict__ w2s8,
    const float* __restrict__ b2,
    float* __restrict__ PL, float* __restrict__ EV, float* __restrict__ VM,
    float* __restrict__ PS, int t0, int rowsC)
{
    __shared__ f16x8 Ah[8][4][64];     // 32 KB
    __shared__ f16x8 Bh[4][384];       // 24 KB
    __shared__ float xt[64][6];
    __shared__ float pls[64], evs[64];
    __shared__ int   srow[64];

    int tid = threadIdx.x;
    int m0 = blockIdx.x * 64;

    // issue first B k-step loads early (overlap with layer-1)
    f16x8 breg[6];
#pragma unroll
    for (int i = 0; i < 6; ++i) breg[i] = w2s8[tid + 256 * i];

    // stage x rows + per-row snow-fraction scalars
    if (tid < 64) {
        int r = tid, row = m0 + r;
        int s = row % 800;
        srow[r] = s;
        const float* xp = &x[((size_t)t0 * 800 + row) * 6];
        float P = xp[0], E = xp[1], T1 = xp[2], T2 = xp[3];
        xt[r][0] = P; xt[r][1] = E; xt[r][2] = T1;
        xt[r][3] = T2; xt[r][4] = xp[4]; xt[r][5] = xp[5];
        float den = T2 - T1;
        float cf = (T1 + T2) / ((den == 0.0f) ? 1.0f : den);
        cf = fminf(fmaxf(cf, -0.999999f), 0.999999f);
        float vf = acosf(cf) * (1.0f / 3.1415f);
        vf = (T1 >= 0.0f) ? 0.0f : vf;
        vf = (T2 <= 0.0f) ? 1.0f : vf;
        pls[r] = P * (1.0f - vf);
        evs[r] = E;
        PS[row] = P * vf;
    }

    // layer-1: thread owns j-range jg*8..+7 for rows rg*8..+7
    int jg = tid & 31, rg = tid >> 5;
    int j0 = jg * 8;
    float w1c[6][8];
#pragma unroll
    for (int c = 0; c < 6; ++c) {
        float4 lo = *(const float4*)&w1T[c * 256 + j0];
        float4 hi = *(const float4*)&w1T[c * 256 + j0 + 4];
        w1c[c][0] = lo.x; w1c[c][1] = lo.y; w1c[c][2] = lo.z; w1c[c][3] = lo.w;
        w1c[c][4] = hi.x; w1c[c][5] = hi.y; w1c[c][6] = hi.z; w1c[c][7] = hi.w;
    }
    __syncthreads();   // xt/srow ready

    int ksw = jg >> 2, kgw = jg & 3;
#pragma unroll
    for (int rr = 0; rr < 8; ++rr) {
        int r = rg * 8 + rr;
        const float* bp = &basec[(size_t)srow[r] * 256 + j0];
        float4 b0 = *(const float4*)bp;
        float4 b1 = *(const float4*)(bp + 4);
        float a[8] = {b0.x, b0.y, b0.z, b0.w, b1.x, b1.y, b1.z, b1.w};
#pragma unroll
        for (int c = 0; c < 6; ++c) {
            float xv = xt[r][c];
#pragma unroll
            for (int e = 0; e < 8; ++e) a[e] = fmaf(xv, w1c[c][e], a[e]);
        }
        f16x8 h;
#pragma unroll
        for (int e = 0; e < 8; ++e) h[e] = (_Float16)tanh_fast(a[e]);
        Ah[ksw][kgw][r] = h;
    }

    // write first B k-step
    f16x8* BhFlat = &Bh[0][0];
#pragma unroll
    for (int i = 0; i < 6; ++i) BhFlat[tid + 256 * i] = breg[i];
    __syncthreads();   // Ah + Bh(ks=0) visible

    int wid = tid >> 6, lane = tid & 63;
    int l15 = lane & 15, l4 = lane >> 4;
    int n0w = wid * 96;

    f32x4 acc[4][6];
#pragma unroll
    for (int nf = 0; nf < 6; ++nf) {
        float bb = b2[n0w + nf * 16 + l15];
#pragma unroll
        for (int mf = 0; mf < 4; ++mf) acc[mf][nf] = (f32x4){bb, bb, bb, bb};
    }

    for (int ks = 0; ks < 8; ++ks) {
        if (ks < 7) {
#pragma unroll
            for (int i = 0; i < 6; ++i)
                breg[i] = w2s8[(size_t)(ks + 1) * 1536 + tid + 256 * i];
        }
        f16x8 af[4], bf[6];
#pragma unroll
        for (int mf = 0; mf < 4; ++mf) af[mf] = Ah[ks][l4][mf * 16 + l15];
#pragma unroll
        for (int nf = 0; nf < 6; ++nf) bf[nf] = Bh[l4][n0w + nf * 16 + l15];
#pragma unroll
        for (int mf = 0; mf < 4; ++mf)
#pragma unroll
            for (int nf = 0; nf < 6; ++nf)
                acc[mf][nf] = __builtin_amdgcn_mfma_f32_16x16x32_f16(
                    af[mf], bf[nf], acc[mf][nf], 0, 0, 0);
        if (ks < 7) {
            __syncthreads();   // readers done with Bh
#pragma unroll
            for (int i = 0; i < 6; ++i) BhFlat[tid + 256 * i] = breg[i];
            __syncthreads();   // next Bh visible
        }
    }

    // epilogue: activation + forcing folding, scalar stores (64B segments)
#pragma unroll
    for (int mf = 0; mf < 4; ++mf) {
#pragma unroll
        for (int nf = 0; nf < 6; ++nf) {
            int colg = n0w + nf * 16 + l15;
            int ch = colg >> 7, cl = colg & 127;
            float* dst = (ch == 0) ? PL : (ch == 1) ? EV : VM;
#pragma unroll
            for (int rr = 0; rr < 4; ++rr) {
                int rl = mf * 16 + l4 * 4 + rr;
                float v = acc[mf][nf][rr];
                float o;
                if (ch == 0)
                    o = pls[rl] * fminf(fmaxf(v * (1.0f / 3.0f) + 0.5f, 0.0f), 1.0f);
                else if (ch == 1)
                    o = evs[rl] * fmaxf(v, 0.0f) * 2.0f;
                else
                    o = __expf(v);
                dst[(size_t)(m0 + rl) * 128 + cl] = o;
            }
        }
    }
}

// ---------------------------------------------------------------------------
// C: sequential reservoir scan + fused FIR routing + ga-reduce.
// 4-deep load pipeline to hide HBM latency (1.5 waves/SIMD occupancy).
// ---------------------------------------------------------------------------
__global__ __launch_bounds__(128) void k_scan(
    const float* __restrict__ PL, const float* __restrict__ EV,
    const float* __restrict__ VM, const float* __restrict__ PS,
    const float* __restrict__ params, const float* __restrict__ rbuf,
    float* __restrict__ state, float* __restrict__ fut,
    float* __restrict__ out, int t0, int Tc, int isFirst)
{
    int s = blockIdx.x, h = threadIdx.x;
    int idx = s * 128 + h;

    float kp = params[0 * NSH + idx];
    float ks = params[1 * NSH + idx];
    float kg = params[2 * NSH + idx];
    float gp = params[3 * NSH + idx];
    float gL = params[4 * NSH + idx];
    float qb = params[5 * NSH + idx];
    float ga = params[6 * NSH + idx];
    float kq = ks * (1.0f - gp);

    float r[NRTAP];
#pragma unroll
    for (int i = 0; i < NRTAP; ++i) r[i] = rbuf[i * NSH + idx];

    float Sf, Ss, Sg, f[NRTAP];
    if (isFirst) {
        Sf = Ss = Sg = 0.0f;
#pragma unroll
        for (int i = 0; i < NRTAP; ++i) f[i] = 0.0f;
    } else {
        Sf = state[idx];
        Ss = state[NSH + idx];
        Sg = state[2 * NSH + idx];
#pragma unroll
        for (int i = 0; i < NRTAP; ++i) f[i] = fut[i * NSH + idx];
    }

    __shared__ float red[2][2];

    float pl[4], ev[4], vm[4], ps[4];
#pragma unroll
    for (int i = 0; i < 4; ++i) {
        if (i < Tc) {
            size_t o = (size_t)i * NSH + idx;
            pl[i] = PL[o]; ev[i] = EV[o]; vm[i] = VM[o]; ps[i] = PS[i * 800 + s];
        } else { pl[i] = ev[i] = vm[i] = ps[i] = 0.0f; }
    }

    for (int tb = 0; tb < Tc; tb += 4) {
        float pln[4], evn[4], vmn[4], psn[4];
#pragma unroll
        for (int i = 0; i < 4; ++i) {
            int t = tb + 4 + i;
            if (t < Tc) {
                size_t o = (size_t)t * NSH + idx;
                pln[i] = PL[o]; evn[i] = EV[o]; vmn[i] = VM[o]; psn[i] = PS[t * 800 + s];
            } else { pln[i] = evn[i] = vmn[i] = psn[i] = 0.0f; }
        }
#pragma unroll
        for (int i = 0; i < 4; ++i) {
            int t = tb + i;
            if (t < Tc) {
                float x1 = Sf + ps[i];
                float qf = fminf(x1, vm[i]);
                Sf = fmaxf(x1 - vm[i], 0.0f);
                float H  = fmaxf(Ss + pl[i] + qf - ev[i], 0.0f);
                float qp = fmaxf(kp * (H - gL), 0.0f);
                float mh = fminf(H, gL);
                float qs = ks * mh;
                Ss = H - qp - qs;
                float qg = fmaf(kg, fmaf(qs, gp, Sg), qb);
                Sg = Sg - qg;
                float qt = qp + kq * mh + qg;

#pragma unroll
                for (int j = 0; j < NRTAP; ++j) f[j] = fmaf(r[j], qt, f[j]);
                float c = ga * f[0];
#pragma unroll
                for (int j = 0; j < NRTAP - 1; ++j) f[j] = f[j + 1];
                f[NRTAP - 1] = 0.0f;

#pragma unroll
                for (int off = 32; off; off >>= 1) c += __shfl_xor(c, off);
                if ((h & 63) == 0) red[t & 1][h >> 6] = c;
                __syncthreads();
                if (h == 0) out[(size_t)(t0 + t) * 800 + s] = red[t & 1][0] + red[t & 1][1];
            }
        }
#pragma unroll
        for (int i = 0; i < 4; ++i) { pl[i] = pln[i]; ev[i] = evn[i]; vm[i] = vmn[i]; ps[i] = psn[i]; }
    }

    state[idx]           = Sf;
    state[NSH + idx]     = Ss;
    state[2 * NSH + idx] = Sg;
#pragma unroll
    for (int i = 0; i < NRTAP; ++i) fut[i * NSH + idx] = f[i];
}

// ---------------------------------------------------------------------------
extern "C" void kernel_launch(void* const* d_in, const int* in_sizes, int n_in,
                              void* d_out, int out_size, void* d_ws, size_t ws_size,
                              hipStream_t stream)
{
    const float* x      = (const float*)d_in[0];
    const float* xc     = (const float*)d_in[1];
    const float* fcW1_w = (const float*)d_in[2];
    const float* fcW1_b = (const float*)d_in[3];
    const float* fcW2_w = (const float*)d_in[4];
    const float* fcW2_b = (const float*)d_in[5];
    const float* fcT1_w = (const float*)d_in[6];
    const float* fcT1_b = (const float*)d_in[7];
    const float* fcT2_w = (const float*)d_in[8];
    const float* fcT2_b = (const float*)d_in[9];
    const float* fcR1_w = (const float*)d_in[10];
    const float* fcR1_b = (const float*)d_in[11];
    const float* fcR2_w = (const float*)d_in[12];
    const float* fcR2_b = (const float*)d_in[13];
    float* out = (float*)d_out;

    float* ws = (float*)d_ws;
    size_t off = 0;
    float* params = ws + off; off += (size_t)7 * NSH;      // 716800
    float* rbuf   = ws + off; off += (size_t)NRTAP * NSH;  // 1536000
    float* basec  = ws + off; off += 800 * 256;
    float* h1w    = ws + off; off += 800 * 256;
    float* h1r    = ws + off; off += 800 * 256;
    float* state  = ws + off; off += (size_t)3 * NSH;
    float* fut    = ws + off; off += (size_t)NRTAP * NSH;
    _Float16* w2s = (_Float16*)(ws + off); off += 49152;   // 98304 fp16
    size_t fixedF = off;                                    // 4,759,552 floats

    long availF = (long)(ws_size / 4) - (long)fixedF;
    long perT   = 800 + (long)3 * NSH;                      // 308,000 floats/step
    int Tc = (int)(availF / perT);
    if (Tc > NTIME) Tc = NTIME;
    Tc &= ~1;                                               // keep rows % 64 == 0
    if (Tc < 2) Tc = 2;

    float* PS = ws + off; off += (size_t)Tc * 800;
    float* PL = ws + off; off += (size_t)Tc * NSH;
    float* EV = ws + off; off += (size_t)Tc * NSH;
    float* VM = ws + off; off += (size_t)Tc * NSH;

    k_prep_w2h<<<384, 256, 0, stream>>>(fcT2_w, w2s);
    k_site_l1<<<800, 256, 0, stream>>>(xc, fcW1_w, fcW1_b, fcR1_w, fcR1_b,
                                       fcT1_w, fcT1_b, h1w, h1r, basec);
    k_whead<<<dim3(100, 7), 128, 0, stream>>>(h1w, fcW2_w, fcW2_b, params);
    k_softmax_ga<<<800, 128, 0, stream>>>(params + (size_t)6 * NSH);
    k_rhead<<<dim3(100, 15), 128, 0, stream>>>(h1r, fcR2_w, fcR2_b, rbuf);

    int nchunk = (NTIME + Tc - 1) / Tc;
    for (int c = 0; c < nchunk; ++c) {
        int t0 = c * Tc;
        int Tcc = NTIME - t0; if (Tcc > Tc) Tcc = Tc;
        int rowsC = Tcc * 800;
        k_timehead_mfma<<<rowsC / 64, 256, 0, stream>>>(
            x, fcT1_w, basec, (const f16x8*)w2s, fcT2_b, PL, EV, VM, PS, t0, rowsC);
        k_scan<<<800, 128, 0, stream>>>(PL, EV, VM, PS, params, rbuf,
                                        state, fut, out, t0, Tcc, c == 0 ? 1 : 0);
    }
}

// Round 3
// 729.410 us; speedup vs baseline: 4.3880x; 1.3632x over previous
//
#include <hip/hip_runtime.h>
#include <cmath>

// WaterNet: NH=128, NG=32, NR=15, NT=730, NS=800
#define NHID 128
#define NSITE 800
#define NTIME 730
#define NRTAP 15
constexpr int NSH = NSITE * NHID;  // 102400

typedef _Float16 f16x8 __attribute__((ext_vector_type(8)));
typedef _Float16 f16x2 __attribute__((ext_vector_type(2)));
typedef float f32x4 __attribute__((ext_vector_type(4)));

__device__ __forceinline__ float tanh_fast(float x) {
    float e = __expf(2.0f * x);
    return 1.0f - 2.0f / (e + 1.0f);
}
__device__ __forceinline__ float sigmoid_fast(float x) {
    return 1.0f / (1.0f + __expf(-x));
}
__device__ __forceinline__ void unpack_h2(unsigned u, float& a, float& b) {
    union { unsigned u; f16x2 h; } cv; cv.u = u;
    a = (float)cv.h.x; b = (float)cv.h.y;
}

// ---------------------------------------------------------------------------
// P0: convert fcT2_w (fp32 [256][384]) to fp16 in MFMA-staging layout:
//   w2s[K0][kg][col][e] , k = K0*32 + kg*8 + e   (f16x8-chunk per (kg,col))
// ---------------------------------------------------------------------------
__global__ void k_prep_w2h(const float* __restrict__ w2, _Float16* __restrict__ w2s)
{
    int idx = blockIdx.x * 256 + threadIdx.x;   // 256*384 = 98304
    if (idx >= 98304) return;
    int k = idx / 384, col = idx - k * 384;
    int K0 = k >> 5, kg = (k >> 3) & 3, e = k & 7;
    w2s[(size_t)K0 * 12288 + kg * 3072 + col * 8 + e] = (_Float16)w2[(size_t)k * 384 + col];
}

// ---------------------------------------------------------------------------
// A1: per-site layer-1 for all three heads.
// ---------------------------------------------------------------------------
__global__ void k_site_l1(const float* __restrict__ xc,
                          const float* __restrict__ w1W, const float* __restrict__ b1W,
                          const float* __restrict__ w1R, const float* __restrict__ b1R,
                          const float* __restrict__ w1T, const float* __restrict__ b1T,
                          float* __restrict__ h1w, float* __restrict__ h1r,
                          float* __restrict__ basec)
{
    __shared__ float xr[32];
    int s = blockIdx.x, j = threadIdx.x;
    if (j < 32) xr[j] = xc[s * 32 + j];
    __syncthreads();
    float aW = b1W[j], aR = b1R[j], aT = b1T[j];
#pragma unroll 8
    for (int k = 0; k < 32; ++k) {
        float xv = xr[k];
        aW = fmaf(xv, w1W[k * 256 + j], aW);
        aR = fmaf(xv, w1R[k * 256 + j], aR);
        aT = fmaf(xv, w1T[(6 + k) * 256 + j], aT);
    }
    h1w[s * 256 + j]   = tanh_fast(aW);
    h1r[s * 256 + j]   = tanh_fast(aR);
    basec[s * 256 + j] = aT;
}

// ---------------------------------------------------------------------------
// A2: static parameter head layer-2 + activations.
// ---------------------------------------------------------------------------
__global__ void k_whead(const float* __restrict__ h1w,
                        const float* __restrict__ w2, const float* __restrict__ b2,
                        float* __restrict__ params)
{
    __shared__ float h[8 * 256];
    int sBase = blockIdx.x * 8, g = blockIdx.y, tid = threadIdx.x;
    for (int p = tid; p < 2048; p += 128) h[p] = h1w[sBase * 256 + p];
    __syncthreads();
    float bias = b2[g * 128 + tid];
    float acc[8];
#pragma unroll
    for (int i = 0; i < 8; ++i) acc[i] = bias;
    for (int k = 0; k < 256; ++k) {
        float wv = w2[k * 896 + g * 128 + tid];
#pragma unroll
        for (int i = 0; i < 8; ++i) acc[i] = fmaf(h[i * 256 + k], wv, acc[i]);
    }
#pragma unroll
    for (int i = 0; i < 8; ++i) {
        float v = acc[i], o;
        if (g == 0 || g == 1 || g == 3)  o = sigmoid_fast(v);
        else if (g == 2)                 o = sigmoid_fast(v) * 0.1f;
        else if (g == 4)                 o = __expf(v) * 2.0f;
        else if (g == 5)                 o = fmaxf(v, 0.0f);
        else                             o = v;  // ga raw (softmax later)
        params[g * NSH + (sBase + i) * 128 + tid] = o;
    }
}

// ---------------------------------------------------------------------------
// A3: softmax of ga over the 128 hidden buckets, in place.
// ---------------------------------------------------------------------------
__global__ void k_softmax_ga(float* __restrict__ ga)
{
    int s = blockIdx.x, h = threadIdx.x;
    float v = ga[s * 128 + h];
    float m = v;
#pragma unroll
    for (int off = 32; off; off >>= 1) m = fmaxf(m, __shfl_xor(m, off));
    __shared__ float ra[2], rb[2];
    if ((h & 63) == 0) ra[h >> 6] = m;
    __syncthreads();
    m = fmaxf(ra[0], ra[1]);
    float e = __expf(v - m);
    float t = e;
#pragma unroll
    for (int off = 32; off; off >>= 1) t += __shfl_xor(t, off);
    if ((h & 63) == 0) rb[h >> 6] = t;
    __syncthreads();
    ga[s * 128 + h] = e / (rb[0] + rb[1]);
}

// ---------------------------------------------------------------------------
// A4: routing head layer-2, r = relu(.), stored as [NRTAP][NSITE*NHID]
// ---------------------------------------------------------------------------
__global__ void k_rhead(const float* __restrict__ h1r,
                        const float* __restrict__ w2, const float* __restrict__ b2,
                        float* __restrict__ rbuf)
{
    __shared__ float h[8 * 256];
    int sBase = blockIdx.x * 8, g = blockIdx.y, tid = threadIdx.x;
    for (int p = tid; p < 2048; p += 128) h[p] = h1r[sBase * 256 + p];
    __syncthreads();
    int c = g * 128 + tid;
    float bias = b2[c];
    float acc[8];
#pragma unroll
    for (int i = 0; i < 8; ++i) acc[i] = bias;
    for (int k = 0; k < 256; ++k) {
        float wv = w2[k * 1920 + c];
#pragma unroll
        for (int i = 0; i < 8; ++i) acc[i] = fmaf(h[i * 256 + k], wv, acc[i]);
    }
    int hh = c / 15, ii = c - hh * 15;
#pragma unroll
    for (int i = 0; i < 8; ++i)
        rbuf[ii * NSH + (sBase + i) * 128 + hh] = fmaxf(acc[i], 0.0f);
}

// ---------------------------------------------------------------------------
// B: time-varying head via fp16 MFMA.
// Block: 64 rows x 384 cols. 4 waves, wave w owns cols [w*96, w*96+96).
// Epilogue packs {pl, ev, vm, ps} as half4 (8B) per (row, bucket) into PB.
// ---------------------------------------------------------------------------
__global__ __launch_bounds__(256, 2) void k_timehead_mfma(
    const float* __restrict__ x, const float* __restrict__ w1T,
    const float* __restrict__ basec, const f16x8* __restrict__ w2s8,
    const float* __restrict__ b2,
    _Float16* __restrict__ PBh, int t0, int rowsC)
{
    __shared__ f16x8 Ah[8][4][64];     // 32 KB
    __shared__ f16x8 Bh[4][384];       // 24 KB
    __shared__ float xt[64][6];
    __shared__ float pls[64], evs[64], pss[64];
    __shared__ int   srow[64];

    int tid = threadIdx.x;
    int m0 = blockIdx.x * 64;

    // issue first B k-step loads early (overlap with layer-1)
    f16x8 breg[6];
#pragma unroll
    for (int i = 0; i < 6; ++i) breg[i] = w2s8[tid + 256 * i];

    // stage x rows + per-row snow-fraction scalars
    if (tid < 64) {
        int r = tid, row = m0 + r;
        int s = row % 800;
        srow[r] = s;
        const float* xp = &x[((size_t)t0 * 800 + row) * 6];
        float P = xp[0], E = xp[1], T1 = xp[2], T2 = xp[3];
        xt[r][0] = P; xt[r][1] = E; xt[r][2] = T1;
        xt[r][3] = T2; xt[r][4] = xp[4]; xt[r][5] = xp[5];
        float den = T2 - T1;
        float cf = (T1 + T2) / ((den == 0.0f) ? 1.0f : den);
        cf = fminf(fmaxf(cf, -0.999999f), 0.999999f);
        float vf = acosf(cf) * (1.0f / 3.1415f);
        vf = (T1 >= 0.0f) ? 0.0f : vf;
        vf = (T2 <= 0.0f) ? 1.0f : vf;
        pls[r] = P * (1.0f - vf);
        evs[r] = E;
        pss[r] = P * vf;
    }

    // layer-1: thread owns j-range jg*8..+7 for rows rg*8..+7
    int jg = tid & 31, rg = tid >> 5;
    int j0 = jg * 8;
    float w1c[6][8];
#pragma unroll
    for (int c = 0; c < 6; ++c) {
        float4 lo = *(const float4*)&w1T[c * 256 + j0];
        float4 hi = *(const float4*)&w1T[c * 256 + j0 + 4];
        w1c[c][0] = lo.x; w1c[c][1] = lo.y; w1c[c][2] = lo.z; w1c[c][3] = lo.w;
        w1c[c][4] = hi.x; w1c[c][5] = hi.y; w1c[c][6] = hi.z; w1c[c][7] = hi.w;
    }
    __syncthreads();   // xt/srow ready

    int ksw = jg >> 2, kgw = jg & 3;
#pragma unroll
    for (int rr = 0; rr < 8; ++rr) {
        int r = rg * 8 + rr;
        const float* bp = &basec[(size_t)srow[r] * 256 + j0];
        float4 b0 = *(const float4*)bp;
        float4 b1 = *(const float4*)(bp + 4);
        float a[8] = {b0.x, b0.y, b0.z, b0.w, b1.x, b1.y, b1.z, b1.w};
#pragma unroll
        for (int c = 0; c < 6; ++c) {
            float xv = xt[r][c];
#pragma unroll
            for (int e = 0; e < 8; ++e) a[e] = fmaf(xv, w1c[c][e], a[e]);
        }
        f16x8 h;
#pragma unroll
        for (int e = 0; e < 8; ++e) h[e] = (_Float16)tanh_fast(a[e]);
        Ah[ksw][kgw][r] = h;
    }

    // write first B k-step
    f16x8* BhFlat = &Bh[0][0];
#pragma unroll
    for (int i = 0; i < 6; ++i) BhFlat[tid + 256 * i] = breg[i];
    __syncthreads();   // Ah + Bh(ks=0) visible

    int wid = tid >> 6, lane = tid & 63;
    int l15 = lane & 15, l4 = lane >> 4;
    int n0w = wid * 96;

    f32x4 acc[4][6];
#pragma unroll
    for (int nf = 0; nf < 6; ++nf) {
        float bb = b2[n0w + nf * 16 + l15];
#pragma unroll
        for (int mf = 0; mf < 4; ++mf) acc[mf][nf] = (f32x4){bb, bb, bb, bb};
    }

    for (int ks = 0; ks < 8; ++ks) {
        if (ks < 7) {
#pragma unroll
            for (int i = 0; i < 6; ++i)
                breg[i] = w2s8[(size_t)(ks + 1) * 1536 + tid + 256 * i];
        }
        f16x8 af[4], bf[6];
#pragma unroll
        for (int mf = 0; mf < 4; ++mf) af[mf] = Ah[ks][l4][mf * 16 + l15];
#pragma unroll
        for (int nf = 0; nf < 6; ++nf) bf[nf] = Bh[l4][n0w + nf * 16 + l15];
#pragma unroll
        for (int mf = 0; mf < 4; ++mf)
#pragma unroll
            for (int nf = 0; nf < 6; ++nf)
                acc[mf][nf] = __builtin_amdgcn_mfma_f32_16x16x32_f16(
                    af[mf], bf[nf], acc[mf][nf], 0, 0, 0);
        if (ks < 7) {
            __syncthreads();   // readers done with Bh
#pragma unroll
            for (int i = 0; i < 6; ++i) BhFlat[tid + 256 * i] = breg[i];
            __syncthreads();   // next Bh visible
        }
    }

    // epilogue: activation + forcing folding; pack into half4 {pl, ev, vm, ps}
#pragma unroll
    for (int mf = 0; mf < 4; ++mf) {
#pragma unroll
        for (int nf = 0; nf < 6; ++nf) {
            int colg = n0w + nf * 16 + l15;
            int ch = colg >> 7, cl = colg & 127;
#pragma unroll
            for (int rr = 0; rr < 4; ++rr) {
                int rl = mf * 16 + l4 * 4 + rr;
                float v = acc[mf][nf][rr];
                float o;
                if (ch == 0)
                    o = pls[rl] * fminf(fmaxf(v * (1.0f / 3.0f) + 0.5f, 0.0f), 1.0f);
                else if (ch == 1)
                    o = evs[rl] * fmaxf(v, 0.0f) * 2.0f;
                else
                    o = fminf(__expf(v), 60000.0f);   // clamp to fp16 range
                size_t base = ((size_t)(m0 + rl) * 128 + cl) * 4;
                PBh[base + ch] = (_Float16)o;
                if (ch == 0) PBh[base + 3] = (_Float16)pss[rl];
            }
        }
    }
}

// ---------------------------------------------------------------------------
// C: sequential reservoir scan + fused FIR routing + ga-reduce.
// NO barrier in the t-loop (barrier => vmcnt(0) drain kills prefetch).
// Wave-local shfl reduce -> LDS partials; single barrier + writeout at end.
// 8-step-deep load pipeline of packed half4 {pl, ev, vm, ps}.
// ---------------------------------------------------------------------------
__global__ __launch_bounds__(128) void k_scan(
    const uint2* __restrict__ PB,
    const float* __restrict__ params, const float* __restrict__ rbuf,
    float* __restrict__ state, float* __restrict__ fut,
    float* __restrict__ out, int t0, int Tc, int isFirst)
{
    __shared__ __align__(16) float part[2][376];

    int s = blockIdx.x, h = threadIdx.x;
    int idx = s * 128 + h;

    float kp = params[0 * NSH + idx];
    float ks = params[1 * NSH + idx];
    float kg = params[2 * NSH + idx];
    float gp = params[3 * NSH + idx];
    float gL = params[4 * NSH + idx];
    float qb = params[5 * NSH + idx];
    float ga = params[6 * NSH + idx];
    float kq = ks * (1.0f - gp);

    float wr[NRTAP];                       // ga folded into FIR taps
#pragma unroll
    for (int i = 0; i < NRTAP; ++i) wr[i] = ga * rbuf[i * NSH + idx];

    float Sf, Ss, Sg, f[NRTAP];
    if (isFirst) {
        Sf = Ss = Sg = 0.0f;
#pragma unroll
        for (int i = 0; i < NRTAP; ++i) f[i] = 0.0f;
    } else {
        Sf = state[idx];
        Ss = state[NSH + idx];
        Sg = state[2 * NSH + idx];
#pragma unroll
        for (int i = 0; i < NRTAP; ++i) f[i] = fut[i * NSH + idx];
    }

    const uint2* pbp = PB + idx;
    const uint2 zz = make_uint2(0u, 0u);

    uint2 A[4], B[4];
#pragma unroll
    for (int i = 0; i < 4; ++i) A[i] = (i < Tc) ? pbp[(size_t)i * NSH] : zz;
#pragma unroll
    for (int i = 0; i < 4; ++i) B[i] = (4 + i < Tc) ? pbp[(size_t)(4 + i) * NSH] : zz;

    int ngroups = (Tc + 3) >> 2;
    for (int g = 0; g < ngroups; ++g) {
        int tb = g * 4;
        uint2 C[4];
#pragma unroll
        for (int i = 0; i < 4; ++i) {
            int t = tb + 8 + i;
            C[i] = (t < Tc) ? pbp[(size_t)t * NSH] : zz;
        }

        float cs[4];
#pragma unroll
        for (int i = 0; i < 4; ++i) {
            float pl, ev, vm, ps;
            unpack_h2(A[i].x, pl, ev);
            unpack_h2(A[i].y, vm, ps);

            float x1 = Sf + ps;
            float qf = fminf(x1, vm);
            Sf = fmaxf(x1 - vm, 0.0f);
            float H  = fmaxf(Ss + pl + qf - ev, 0.0f);
            float qp = fmaxf(kp * (H - gL), 0.0f);
            float mh = fminf(H, gL);
            float qs = ks * mh;
            Ss = H - qp - qs;
            float qg = fmaf(kg, fmaf(qs, gp, Sg), qb);
            Sg = Sg - qg;
            float qt = qp + kq * mh + qg;

#pragma unroll
            for (int j = 0; j < NRTAP; ++j) f[j] = fmaf(wr[j], qt, f[j]);
            cs[i] = f[0];
#pragma unroll
            for (int j = 0; j < NRTAP - 1; ++j) f[j] = f[j + 1];
            f[NRTAP - 1] = 0.0f;
        }

        // 4 independent wave-local reduces (ILP across the shfl chains)
#pragma unroll
        for (int i = 0; i < 4; ++i) {
            float c = cs[i];
#pragma unroll
            for (int off = 32; off; off >>= 1) c += __shfl_xor(c, off);
            cs[i] = c;
        }
        if ((h & 63) == 0)
            *(float4*)&part[h >> 6][tb] = make_float4(cs[0], cs[1], cs[2], cs[3]);

#pragma unroll
        for (int i = 0; i < 4; ++i) { A[i] = B[i]; B[i] = C[i]; }
    }

    state[idx]           = Sf;
    state[NSH + idx]     = Ss;
    state[2 * NSH + idx] = Sg;
#pragma unroll
    for (int i = 0; i < NRTAP; ++i) fut[i * NSH + idx] = f[i];

    __syncthreads();    // the ONLY block-wide sync
    for (int t = h; t < Tc; t += 128)
        out[(size_t)(t0 + t) * 800 + s] = part[0][t] + part[1][t];
}

// ---------------------------------------------------------------------------
extern "C" void kernel_launch(void* const* d_in, const int* in_sizes, int n_in,
                              void* d_out, int out_size, void* d_ws, size_t ws_size,
                              hipStream_t stream)
{
    const float* x      = (const float*)d_in[0];
    const float* xc     = (const float*)d_in[1];
    const float* fcW1_w = (const float*)d_in[2];
    const float* fcW1_b = (const float*)d_in[3];
    const float* fcW2_w = (const float*)d_in[4];
    const float* fcW2_b = (const float*)d_in[5];
    const float* fcT1_w = (const float*)d_in[6];
    const float* fcT1_b = (const float*)d_in[7];
    const float* fcT2_w = (const float*)d_in[8];
    const float* fcT2_b = (const float*)d_in[9];
    const float* fcR1_w = (const float*)d_in[10];
    const float* fcR1_b = (const float*)d_in[11];
    const float* fcR2_w = (const float*)d_in[12];
    const float* fcR2_b = (const float*)d_in[13];
    float* out = (float*)d_out;

    float* ws = (float*)d_ws;
    size_t off = 0;
    float* params = ws + off; off += (size_t)7 * NSH;      // 716800
    float* rbuf   = ws + off; off += (size_t)NRTAP * NSH;  // 1536000
    float* basec  = ws + off; off += 800 * 256;
    float* h1w    = ws + off; off += 800 * 256;
    float* h1r    = ws + off; off += 800 * 256;
    float* state  = ws + off; off += (size_t)3 * NSH;
    float* fut    = ws + off; off += (size_t)NRTAP * NSH;
    _Float16* w2s = (_Float16*)(ws + off); off += 49152;   // 98304 fp16
    size_t fixedF = off;

    long availF = (long)(ws_size / 4) - (long)fixedF;
    long perT   = (long)2 * NSH;                            // 204800 floats/step (half4)
    int Tc = (int)(availF / perT);
    Tc &= ~3;                                               // multiple of 4
    if (Tc > 368) Tc = 368;                                 // LDS part[] bound
    if (Tc < 4) Tc = 4;

    _Float16* PBh = (_Float16*)(ws + off); off += (size_t)Tc * perT;

    k_prep_w2h<<<384, 256, 0, stream>>>(fcT2_w, w2s);
    k_site_l1<<<800, 256, 0, stream>>>(xc, fcW1_w, fcW1_b, fcR1_w, fcR1_b,
                                       fcT1_w, fcT1_b, h1w, h1r, basec);
    k_whead<<<dim3(100, 7), 128, 0, stream>>>(h1w, fcW2_w, fcW2_b, params);
    k_softmax_ga<<<800, 128, 0, stream>>>(params + (size_t)6 * NSH);
    k_rhead<<<dim3(100, 15), 128, 0, stream>>>(h1r, fcR2_w, fcR2_b, rbuf);

    int nchunk = (NTIME + Tc - 1) / Tc;
    for (int c = 0; c < nchunk; ++c) {
        int t0 = c * Tc;
        int Tcc = NTIME - t0; if (Tcc > Tc) Tcc = Tc;
        int rowsC = Tcc * 800;
        k_timehead_mfma<<<rowsC / 64, 256, 0, stream>>>(
            x, fcT1_w, basec, (const f16x8*)w2s, fcT2_b, PBh, t0, rowsC);
        k_scan<<<800, 128, 0, stream>>>((const uint2*)PBh, params, rbuf,
                                        state, fut, out, t0, Tcc, c == 0 ? 1 : 0);
    }
}